// Round 2
// baseline (4072.397 us; speedup 1.0000x reference)
//
#include <hip/hip_runtime.h>
#include <cstdint>
#include <cmath>

// LSTM: B=64, T=2048, H=128, gates=4H=512. f32 throughout.
// Round 2: force W-row register residency (R1 failure: VGPR_Count=80 => compiler
// rematerialized the 128-float weight row from memory every step).
//   - amdgpu_waves_per_eu(2,2): stop the backend trading registers for occupancy.
//   - 32 named float4 weight registers (macro-expanded), 4 independent accumulators.
// Decomposition unchanged:
//   xproj_kernel: xg[b][t][j] = dot(W_ih[j], x[b][t]) + b_ih[j] + b_hh[j]
//   lstm_rec_kernel: 64 blocks (1 per batch chain), 512 threads (thread j owns gate j).
// Floor arithmetic: rec = 2048 steps x 512 cy (65536 FMA / 128 FMA-per-cy-per-CU)
//                       = 1.05M cy ~= 437 us. Target this round ~520-650 us.

#define HID 128
#define G4  512
#define BB  64
#define TT  2048

#define DECL_W(wr) \
    float4 w0=(wr)[0],  w1=(wr)[1],  w2=(wr)[2],  w3=(wr)[3],  \
           w4=(wr)[4],  w5=(wr)[5],  w6=(wr)[6],  w7=(wr)[7],  \
           w8=(wr)[8],  w9=(wr)[9],  w10=(wr)[10],w11=(wr)[11],\
           w12=(wr)[12],w13=(wr)[13],w14=(wr)[14],w15=(wr)[15],\
           w16=(wr)[16],w17=(wr)[17],w18=(wr)[18],w19=(wr)[19],\
           w20=(wr)[20],w21=(wr)[21],w22=(wr)[22],w23=(wr)[23],\
           w24=(wr)[24],w25=(wr)[25],w26=(wr)[26],w27=(wr)[27],\
           w28=(wr)[28],w29=(wr)[29],w30=(wr)[30],w31=(wr)[31];

// 4 independent accumulators (a0..a3) break the fma dependency chain.
#define DOT1(i) { const float4 v = h4[i];              \
    a0 = fmaf(w##i.x, v.x, a0); a1 = fmaf(w##i.y, v.y, a1); \
    a2 = fmaf(w##i.z, v.z, a2); a3 = fmaf(w##i.w, v.w, a3); }

#define DOT_ALL \
    DOT1(0)  DOT1(1)  DOT1(2)  DOT1(3)  DOT1(4)  DOT1(5)  DOT1(6)  DOT1(7)  \
    DOT1(8)  DOT1(9)  DOT1(10) DOT1(11) DOT1(12) DOT1(13) DOT1(14) DOT1(15) \
    DOT1(16) DOT1(17) DOT1(18) DOT1(19) DOT1(20) DOT1(21) DOT1(22) DOT1(23) \
    DOT1(24) DOT1(25) DOT1(26) DOT1(27) DOT1(28) DOT1(29) DOT1(30) DOT1(31)

__global__ __launch_bounds__(512)
__attribute__((amdgpu_waves_per_eu(2, 2)))
void xproj_kernel(const float* __restrict__ x, const float* __restrict__ W_ih,
                  const float* __restrict__ b_ih, const float* __restrict__ b_hh,
                  float* __restrict__ xg, int t0, int Tc) {
    __shared__ __align__(16) float xs[64 * HID];   // 64 (b,t)-rows of x
    const int j  = threadIdx.x;                    // gate row 0..511
    const int r0 = blockIdx.x * 64;                // first row of this tile
    const int b   = r0 / Tc;                       // Tc % 64 == 0 -> tile within one b
    const int tc0 = r0 % Tc;

    // stage 64 x-rows (contiguous: same b, consecutive t)
    const float* xsrc = x + ((size_t)b * TT + (size_t)t0 + tc0) * HID;
    #pragma unroll
    for (int i = 0; i < 4; ++i) {
        const int lin = (i * 512 + j) * 4;         // coalesced float4
        *reinterpret_cast<float4*>(&xs[lin]) =
            *reinterpret_cast<const float4*>(&xsrc[lin]);
    }

    const float4* wr = reinterpret_cast<const float4*>(W_ih + (size_t)j * HID);
    DECL_W(wr)
    const float bias = b_ih[j] + b_hh[j];
    __syncthreads();

    float* dst = xg + ((size_t)b * Tc + tc0) * G4 + j;
    for (int r = 0; r < 64; ++r) {
        const float4* h4 = reinterpret_cast<const float4*>(&xs[r * HID]);
        float a0 = bias, a1 = 0.f, a2 = 0.f, a3 = 0.f;
        DOT_ALL
        dst[(size_t)r * G4] = (a0 + a1) + (a2 + a3);   // coalesced across j
    }
}

__global__ __launch_bounds__(512)
__attribute__((amdgpu_waves_per_eu(2, 2)))
void lstm_rec_kernel(const float* __restrict__ xg, const float* __restrict__ h0,
                     const float* __restrict__ c0, const float* __restrict__ W_hh,
                     float* __restrict__ out, float* __restrict__ hstate,
                     float* __restrict__ cstate, int t0, int Tc) {
    __shared__ __align__(16) float h_lds[HID];
    __shared__ __align__(16) float g_lds[G4];
    const int j = threadIdx.x;
    const int b = blockIdx.x;

    const float4* wr = reinterpret_cast<const float4*>(W_hh + (size_t)j * HID);
    DECL_W(wr)

    float c = 0.f;
    if (j < HID) {
        h_lds[j] = (t0 == 0) ? h0[b * HID + j] : hstate[b * HID + j];
        c        = (t0 == 0) ? c0[b * HID + j] : cstate[b * HID + j];
    }
    __syncthreads();

    const float* xgb  = xg  + (size_t)b * Tc * G4 + j;
    float*       outb = out + ((size_t)b * TT + t0) * HID;

    float xnext = xgb[0];                          // prefetched xg for step 0
    for (int tc = 0; tc < Tc; ++tc) {
        float a0 = xnext, a1 = 0.f, a2 = 0.f, a3 = 0.f;
        if (tc + 1 < Tc) xnext = xgb[(size_t)(tc + 1) * G4];  // issue early

        const float4* h4 = reinterpret_cast<const float4*>(h_lds);
        DOT_ALL
        g_lds[j] = (a0 + a1) + (a2 + a3);
        __syncthreads();                           // gates ready; h_lds reads done

        if (j < HID) {
            const float gi = g_lds[j];
            const float gf = g_lds[j +     HID];
            const float gg = g_lds[j + 2 * HID];
            const float go = g_lds[j + 3 * HID];
            const float i_ = 1.f / (1.f + __expf(-gi));
            const float f_ = 1.f / (1.f + __expf(-gf));
            const float g_ = tanhf(gg);
            const float o_ = 1.f / (1.f + __expf(-go));
            c = f_ * c + i_ * g_;
            const float h = o_ * tanhf(c);
            h_lds[j] = h;
            outb[(size_t)tc * HID + j] = h;        // coalesced 512B store
        }
        __syncthreads();                           // h ready for next step
    }
    if (j < HID) {
        hstate[b * HID + j] = h_lds[j];
        cstate[b * HID + j] = c;
    }
}

extern "C" void kernel_launch(void* const* d_in, const int* in_sizes, int n_in,
                              void* d_out, int out_size, void* d_ws, size_t ws_size,
                              hipStream_t stream) {
    const float* x    = (const float*)d_in[0];
    const float* h0   = (const float*)d_in[1];
    const float* c0   = (const float*)d_in[2];
    const float* W_ih = (const float*)d_in[3];
    const float* W_hh = (const float*)d_in[4];
    const float* b_ih = (const float*)d_in[5];
    const float* b_hh = (const float*)d_in[6];
    float* out = (float*)d_out;

    char*  ws     = (char*)d_ws;
    float* hstate = (float*)ws;                    // 64*128*4 = 32 KB
    float* cstate = (float*)(ws + 32768);          // 32 KB
    float* xg     = (float*)(ws + 65536);

    const size_t per_t = (size_t)BB * G4 * sizeof(float);   // 128 KB per timestep
    size_t avail = ws_size > 65536 ? ws_size - 65536 : 0;
    long long tc_ll = (long long)(avail / per_t);
    int Tc = tc_ll > TT ? TT : (int)tc_ll;
    Tc = (Tc / 64) * 64;
    if (Tc < 64) Tc = 64;                          // minimum chunk (~8.5 MB ws)

    for (int t0 = 0; t0 < TT; t0 += Tc) {
        const int Tcur = (TT - t0 < Tc) ? (TT - t0) : Tc;
        xproj_kernel<<<dim3(Tcur), dim3(512), 0, stream>>>(x, W_ih, b_ih, b_hh, xg, t0, Tcur);
        lstm_rec_kernel<<<dim3(BB), dim3(512), 0, stream>>>(xg, h0, c0, W_hh, out,
                                                            hstate, cstate, t0, Tcur);
    }
}

// Round 3
// 2558.671 us; speedup vs baseline: 1.5916x; 1.5916x over previous
//
#include <hip/hip_runtime.h>
#include <cstdint>
#include <cmath>

// LSTM: B=64, T=2048, H=128, gates=4H=512. f32 throughout (precision: per-step
// noise is amplified ~1e3x through the 2048-step chain; f16/bf16 in the
// recurrence would blow the absmax threshold).
//
// Round 3 theory: R1/R2 showed the allocator caps this kernel near ~100 VGPRs
// and pressure-aware LICM then leaves weight loads INSIDE the step loop
// (256 KB/step/CU from L2, latency-bound, VALUBusy 10%). Fix: k-split so each
// thread needs only 64 weight floats (16 float4 = 64 VGPR, total ~90 < 128
// budget at waves_per_eu(4,4)).
//   lstm_rec_kernel: 64 blocks x 1024 threads. thread (j = t&511, kh = t>>9)
//     owns W_hh[j][kh*64 .. kh*64+63]. Partials combined via LDS float2.
//   xproj_kernel: 512 threads, 16-row x-tile, two 64-wide weight passes,
//     16 accumulators.

#define HID 128
#define G4  512
#define BB  64
#define TT  2048

#define DECL_W16(p) \
    float4 w0=(p)[0],  w1=(p)[1],  w2=(p)[2],  w3=(p)[3],  \
           w4=(p)[4],  w5=(p)[5],  w6=(p)[6],  w7=(p)[7],  \
           w8=(p)[8],  w9=(p)[9],  w10=(p)[10],w11=(p)[11],\
           w12=(p)[12],w13=(p)[13],w14=(p)[14],w15=(p)[15];

#define LOAD_W16(p) \
    w0=(p)[0];  w1=(p)[1];  w2=(p)[2];  w3=(p)[3];  \
    w4=(p)[4];  w5=(p)[5];  w6=(p)[6];  w7=(p)[7];  \
    w8=(p)[8];  w9=(p)[9];  w10=(p)[10];w11=(p)[11];\
    w12=(p)[12];w13=(p)[13];w14=(p)[14];w15=(p)[15];

#define FMA4(i) { const float4 v = hp[i];                      \
    a0 = fmaf(w##i.x, v.x, a0); a1 = fmaf(w##i.y, v.y, a1);     \
    a2 = fmaf(w##i.z, v.z, a2); a3 = fmaf(w##i.w, v.w, a3); }

#define DOT64 \
    FMA4(0)  FMA4(1)  FMA4(2)  FMA4(3)  FMA4(4)  FMA4(5)  FMA4(6)  FMA4(7) \
    FMA4(8)  FMA4(9)  FMA4(10) FMA4(11) FMA4(12) FMA4(13) FMA4(14) FMA4(15)

__global__ __launch_bounds__(512)
__attribute__((amdgpu_waves_per_eu(4, 4)))
void xproj_kernel(const float* __restrict__ x, const float* __restrict__ W_ih,
                  const float* __restrict__ b_ih, const float* __restrict__ b_hh,
                  float* __restrict__ xg, int t0, int Tc) {
    __shared__ __align__(16) float xs[16 * HID];   // 16 (b,t)-rows of x, 8 KB
    const int j    = threadIdx.x;                  // gate 0..511
    const int row0 = blockIdx.x * 16;              // Tc % 16 == 0 -> tile in one b
    const int b    = row0 / Tc;
    const int tc0  = row0 % Tc;

    const float* xsrc = x + ((size_t)b * TT + (size_t)t0 + tc0) * HID;
    reinterpret_cast<float4*>(xs)[j] =
        reinterpret_cast<const float4*>(xsrc)[j];  // 512 float4 = whole tile

    const float bias = b_ih[j] + b_hh[j];
    const float4* wr = reinterpret_cast<const float4*>(W_ih + (size_t)j * HID);
    DECL_W16(wr)                                   // W_ih[j][0:64]
    __syncthreads();

    float acc[16];
    #pragma unroll
    for (int r = 0; r < 16; ++r) acc[r] = bias;

    #pragma unroll
    for (int r = 0; r < 16; ++r) {                 // pass 0: k = 0..63
        const float4* hp = reinterpret_cast<const float4*>(&xs[r * HID]);
        float a0 = 0.f, a1 = 0.f, a2 = 0.f, a3 = 0.f;
        DOT64
        acc[r] += (a0 + a1) + (a2 + a3);
    }
    LOAD_W16(wr + 16)                              // W_ih[j][64:128]
    #pragma unroll
    for (int r = 0; r < 16; ++r) {                 // pass 1: k = 64..127
        const float4* hp = reinterpret_cast<const float4*>(&xs[r * HID]) + 16;
        float a0 = 0.f, a1 = 0.f, a2 = 0.f, a3 = 0.f;
        DOT64
        acc[r] += (a0 + a1) + (a2 + a3);
    }

    float* dst = xg + ((size_t)b * Tc + tc0) * G4 + j;
    #pragma unroll
    for (int r = 0; r < 16; ++r)
        dst[(size_t)r * G4] = acc[r];              // coalesced across j
}

__global__ __launch_bounds__(1024)
__attribute__((amdgpu_waves_per_eu(4, 4)))
void lstm_rec_kernel(const float* __restrict__ xg, const float* __restrict__ h0,
                     const float* __restrict__ c0, const float* __restrict__ W_hh,
                     float* __restrict__ out, float* __restrict__ hstate,
                     float* __restrict__ cstate, int t0, int Tc) {
    __shared__ __align__(16) float  h_lds[HID];    // current hidden state
    __shared__ __align__(16) float2 part2[G4];     // k-half partial sums
    const int t  = threadIdx.x;
    const int j  = t & 511;                        // gate
    const int kh = t >> 9;                         // k-half (wave-uniform)
    const int b  = blockIdx.x;

    const float4* wr =
        reinterpret_cast<const float4*>(W_hh + (size_t)j * HID + kh * 64);
    DECL_W16(wr)                                   // 64 weights -> 64 VGPR

    float c = 0.f;
    if (t < HID) {
        h_lds[t] = (t0 == 0) ? h0[b * HID + t] : hstate[b * HID + t];
        c        = (t0 == 0) ? c0[b * HID + t] : cstate[b * HID + t];
    }
    __syncthreads();

    const float* xgb  = xg  + (size_t)b * Tc * G4 + j;
    float*       outb = out + ((size_t)b * TT + t0) * HID;

    float xnext = (kh == 0) ? xgb[0] : 0.f;        // prefetched xg (kh0 only)
    for (int tc = 0; tc < Tc; ++tc) {
        float a0 = xnext, a1 = 0.f, a2 = 0.f, a3 = 0.f;
        if (kh == 0 && tc + 1 < Tc)                // wave-uniform branch
            xnext = xgb[(size_t)(tc + 1) * G4];    // issue next-step load early

        const float4* hp = reinterpret_cast<const float4*>(h_lds) + (kh << 4);
        DOT64
        reinterpret_cast<float*>(part2)[(j << 1) | kh] = (a0 + a1) + (a2 + a3);
        __syncthreads();                           // partials ready; h reads done

        if (t < HID) {
            const float2 pi = part2[t];
            const float2 pf = part2[t +     HID];
            const float2 pg = part2[t + 2 * HID];
            const float2 po = part2[t + 3 * HID];
            const float gi = pi.x + pi.y;
            const float gf = pf.x + pf.y;
            const float gg = pg.x + pg.y;
            const float go = po.x + po.y;
            const float i_ = 1.f / (1.f + __expf(-gi));
            const float f_ = 1.f / (1.f + __expf(-gf));
            const float g_ = tanhf(gg);
            const float o_ = 1.f / (1.f + __expf(-go));
            c = f_ * c + i_ * g_;
            const float h = o_ * tanhf(c);
            h_lds[t] = h;                          // safe: all h reads pre-barrier
            outb[(size_t)tc * HID + t] = h;
        }
        __syncthreads();                           // h ready; part2 reusable
    }
    if (t < HID) {
        hstate[b * HID + t] = h_lds[t];
        cstate[b * HID + t] = c;
    }
}

extern "C" void kernel_launch(void* const* d_in, const int* in_sizes, int n_in,
                              void* d_out, int out_size, void* d_ws, size_t ws_size,
                              hipStream_t stream) {
    const float* x    = (const float*)d_in[0];
    const float* h0   = (const float*)d_in[1];
    const float* c0   = (const float*)d_in[2];
    const float* W_ih = (const float*)d_in[3];
    const float* W_hh = (const float*)d_in[4];
    const float* b_ih = (const float*)d_in[5];
    const float* b_hh = (const float*)d_in[6];
    float* out = (float*)d_out;

    char*  ws     = (char*)d_ws;
    float* hstate = (float*)ws;                    // 64*128*4 = 32 KB
    float* cstate = (float*)(ws + 32768);          // 32 KB
    float* xg     = (float*)(ws + 65536);

    const size_t per_t = (size_t)BB * G4 * sizeof(float);   // 128 KB per timestep
    size_t avail = ws_size > 65536 ? ws_size - 65536 : 0;
    long long tc_ll = (long long)(avail / per_t);
    int Tc = tc_ll > TT ? TT : (int)tc_ll;
    Tc = (Tc / 64) * 64;
    if (Tc < 64) Tc = 64;                          // minimum chunk (~8.5 MB ws)

    for (int t0 = 0; t0 < TT; t0 += Tc) {
        const int Tcur = (TT - t0 < Tc) ? (TT - t0) : Tc;
        // xproj: 16 rows per block -> (BB*Tcur)/16 = 4*Tcur blocks
        xproj_kernel<<<dim3(4 * Tcur), dim3(512), 0, stream>>>(x, W_ih, b_ih, b_hh,
                                                               xg, t0, Tcur);
        lstm_rec_kernel<<<dim3(BB), dim3(1024), 0, stream>>>(xg, h0, c0, W_hh, out,
                                                             hstate, cstate, t0, Tcur);
    }
}

// Round 4
// 2465.295 us; speedup vs baseline: 1.6519x; 1.0379x over previous
//
#include <hip/hip_runtime.h>
#include <cstdint>
#include <cmath>

// LSTM: B=64, T=2048, H=128, gates=4H=512. f32 throughout (precision: per-step
// noise is amplified through the 2048-step chain; keep the recurrence f32).
//
// Round 4 theory: R1-R3 all show VGPR_Count ~= (demand minus weights) + 40 --
// the backend treats the loop-invariant __restrict__ weight loads as
// REMATERIALIZABLE and re-issues them inside the 2048-step loop (L2-latency
// bound, 2500 cy/step vs 512-cy FMA floor). Fix: opaque asm identity on each
// weight component => value becomes asm-defined, not remat-able => must stay
// in VGPRs. Demand ~104 < 128 budget at waves_per_eu(4,4).
//   lstm_rec_kernel: 64 blocks x 1024 threads; thread (j=t&511, kh=t>>9) owns
//     W_hh[j][kh*64..+63] in 16 pinned float4s. Partials combined via LDS.
//   xproj_kernel: 512 threads, 16-row x-tile, two 64-wide pinned weight passes.

#define HID 128
#define G4  512
#define BB  64
#define TT  2048

#define DECL_W16(p) \
    float4 w0=(p)[0],  w1=(p)[1],  w2=(p)[2],  w3=(p)[3],  \
           w4=(p)[4],  w5=(p)[5],  w6=(p)[6],  w7=(p)[7],  \
           w8=(p)[8],  w9=(p)[9],  w10=(p)[10],w11=(p)[11],\
           w12=(p)[12],w13=(p)[13],w14=(p)[14],w15=(p)[15];

#define LOAD_W16(p) \
    w0=(p)[0];  w1=(p)[1];  w2=(p)[2];  w3=(p)[3];  \
    w4=(p)[4];  w5=(p)[5];  w6=(p)[6];  w7=(p)[7];  \
    w8=(p)[8];  w9=(p)[9];  w10=(p)[10];w11=(p)[11];\
    w12=(p)[12];w13=(p)[13];w14=(p)[14];w15=(p)[15];

// Opaque identity: value becomes asm-defined -> compiler cannot rematerialize
// it by re-loading from memory inside the loop. Forces VGPR residency.
#define PIN4(v) asm volatile("" : "+v"((v).x), "+v"((v).y), "+v"((v).z), "+v"((v).w))
#define PIN_W16 \
    PIN4(w0);  PIN4(w1);  PIN4(w2);  PIN4(w3);  PIN4(w4);  PIN4(w5);  \
    PIN4(w6);  PIN4(w7);  PIN4(w8);  PIN4(w9);  PIN4(w10); PIN4(w11); \
    PIN4(w12); PIN4(w13); PIN4(w14); PIN4(w15);

#define FMA4(i) { const float4 v = hp[i];                      \
    a0 = fmaf(w##i.x, v.x, a0); a1 = fmaf(w##i.y, v.y, a1);     \
    a2 = fmaf(w##i.z, v.z, a2); a3 = fmaf(w##i.w, v.w, a3); }

#define DOT64 \
    FMA4(0)  FMA4(1)  FMA4(2)  FMA4(3)  FMA4(4)  FMA4(5)  FMA4(6)  FMA4(7) \
    FMA4(8)  FMA4(9)  FMA4(10) FMA4(11) FMA4(12) FMA4(13) FMA4(14) FMA4(15)

__device__ __forceinline__ float sigm_fast(float x) {
    return 1.f / (1.f + __expf(-x));
}
__device__ __forceinline__ float tanh_fast(float x) {
    // 1 - 2/(1+e^{2x}); exact limits at +-inf, ~1ulp f32 error elsewhere.
    return 1.f - 2.f / (1.f + __expf(2.f * x));
}

__global__ __launch_bounds__(512)
__attribute__((amdgpu_waves_per_eu(4, 4)))
void xproj_kernel(const float* __restrict__ x, const float* __restrict__ W_ih,
                  const float* __restrict__ b_ih, const float* __restrict__ b_hh,
                  float* __restrict__ xg, int t0, int Tc) {
    __shared__ __align__(16) float xs[16 * HID];   // 16 (b,t)-rows of x, 8 KB
    const int j    = threadIdx.x;                  // gate 0..511
    const int row0 = blockIdx.x * 16;              // Tc % 16 == 0 -> tile in one b
    const int b    = row0 / Tc;
    const int tc0  = row0 % Tc;

    const float* xsrc = x + ((size_t)b * TT + (size_t)t0 + tc0) * HID;
    reinterpret_cast<float4*>(xs)[j] =
        reinterpret_cast<const float4*>(xsrc)[j];  // 512 float4 = whole tile

    const float bias = b_ih[j] + b_hh[j];
    const float4* wr = reinterpret_cast<const float4*>(W_ih + (size_t)j * HID);
    DECL_W16(wr)                                   // W_ih[j][0:64]
    PIN_W16
    __syncthreads();

    float acc[16];
    #pragma unroll
    for (int r = 0; r < 16; ++r) acc[r] = bias;

    #pragma unroll
    for (int r = 0; r < 16; ++r) {                 // pass 0: k = 0..63
        const float4* hp = reinterpret_cast<const float4*>(&xs[r * HID]);
        float a0 = 0.f, a1 = 0.f, a2 = 0.f, a3 = 0.f;
        DOT64
        acc[r] += (a0 + a1) + (a2 + a3);
    }
    LOAD_W16(wr + 16)                              // W_ih[j][64:128]
    PIN_W16
    #pragma unroll
    for (int r = 0; r < 16; ++r) {                 // pass 1: k = 64..127
        const float4* hp = reinterpret_cast<const float4*>(&xs[r * HID]) + 16;
        float a0 = 0.f, a1 = 0.f, a2 = 0.f, a3 = 0.f;
        DOT64
        acc[r] += (a0 + a1) + (a2 + a3);
    }

    float* dst = xg + ((size_t)b * Tc + tc0) * G4 + j;
    #pragma unroll
    for (int r = 0; r < 16; ++r)
        dst[(size_t)r * G4] = acc[r];              // coalesced across j
}

__global__ __launch_bounds__(1024)
__attribute__((amdgpu_waves_per_eu(4, 4)))
void lstm_rec_kernel(const float* __restrict__ xg, const float* __restrict__ h0,
                     const float* __restrict__ c0, const float* __restrict__ W_hh,
                     float* __restrict__ out, float* __restrict__ hstate,
                     float* __restrict__ cstate, int t0, int Tc) {
    __shared__ __align__(16) float  h_lds[HID];    // current hidden state
    __shared__ __align__(16) float2 part2[G4];     // k-half partial sums
    const int t  = threadIdx.x;
    const int j  = t & 511;                        // gate
    const int kh = t >> 9;                         // k-half (wave-uniform)
    const int b  = blockIdx.x;

    const float4* wr =
        reinterpret_cast<const float4*>(W_hh + (size_t)j * HID + kh * 64);
    DECL_W16(wr)                                   // 64 weights
    PIN_W16                                        // ...pinned in 64 VGPRs

    float c = 0.f;
    if (t < HID) {
        h_lds[t] = (t0 == 0) ? h0[b * HID + t] : hstate[b * HID + t];
        c        = (t0 == 0) ? c0[b * HID + t] : cstate[b * HID + t];
    }
    __syncthreads();

    const float* xgb  = xg  + (size_t)b * Tc * G4 + j;
    float*       outb = out + ((size_t)b * TT + t0) * HID;

    float xnext = (kh == 0) ? xgb[0] : 0.f;        // prefetched xg (kh0 only)
    for (int tc = 0; tc < Tc; ++tc) {
        float a0 = xnext, a1 = 0.f, a2 = 0.f, a3 = 0.f;
        if (kh == 0 && tc + 1 < Tc)                // wave-uniform branch
            xnext = xgb[(size_t)(tc + 1) * G4];    // issue next-step load early

        const float4* hp = reinterpret_cast<const float4*>(h_lds) + (kh << 4);
        DOT64
        reinterpret_cast<float*>(part2)[(j << 1) | kh] = (a0 + a1) + (a2 + a3);
        __syncthreads();                           // partials ready; h reads done

        if (t < HID) {
            const float2 pi = part2[t];
            const float2 pf = part2[t +     HID];
            const float2 pg = part2[t + 2 * HID];
            const float2 po = part2[t + 3 * HID];
            const float i_ = sigm_fast(pi.x + pi.y);
            const float f_ = sigm_fast(pf.x + pf.y);
            const float g_ = tanh_fast(pg.x + pg.y);
            const float o_ = sigm_fast(po.x + po.y);
            c = f_ * c + i_ * g_;
            const float h = o_ * tanh_fast(c);
            h_lds[t] = h;                          // safe: all h reads pre-barrier
            outb[(size_t)tc * HID + t] = h;
        }
        __syncthreads();                           // h ready; part2 reusable
    }
    if (t < HID) {
        hstate[b * HID + t] = h_lds[t];
        cstate[b * HID + t] = c;
    }
}

extern "C" void kernel_launch(void* const* d_in, const int* in_sizes, int n_in,
                              void* d_out, int out_size, void* d_ws, size_t ws_size,
                              hipStream_t stream) {
    const float* x    = (const float*)d_in[0];
    const float* h0   = (const float*)d_in[1];
    const float* c0   = (const float*)d_in[2];
    const float* W_ih = (const float*)d_in[3];
    const float* W_hh = (const float*)d_in[4];
    const float* b_ih = (const float*)d_in[5];
    const float* b_hh = (const float*)d_in[6];
    float* out = (float*)d_out;

    char*  ws     = (char*)d_ws;
    float* hstate = (float*)ws;                    // 64*128*4 = 32 KB
    float* cstate = (float*)(ws + 32768);          // 32 KB
    float* xg     = (float*)(ws + 65536);

    const size_t per_t = (size_t)BB * G4 * sizeof(float);   // 128 KB per timestep
    size_t avail = ws_size > 65536 ? ws_size - 65536 : 0;
    long long tc_ll = (long long)(avail / per_t);
    int Tc = tc_ll > TT ? TT : (int)tc_ll;
    Tc = (Tc / 64) * 64;
    if (Tc < 64) Tc = 64;                          // minimum chunk (~8.5 MB ws)

    for (int t0 = 0; t0 < TT; t0 += Tc) {
        const int Tcur = (TT - t0 < Tc) ? (TT - t0) : Tc;
        // xproj: 16 rows per block -> (BB*Tcur)/16 = 4*Tcur blocks
        xproj_kernel<<<dim3(4 * Tcur), dim3(512), 0, stream>>>(x, W_ih, b_ih, b_hh,
                                                               xg, t0, Tcur);
        lstm_rec_kernel<<<dim3(BB), dim3(1024), 0, stream>>>(xg, h0, c0, W_hh, out,
                                                             hstate, cstate, t0, Tcur);
    }
}

// Round 5
// 2302.084 us; speedup vs baseline: 1.7690x; 1.0709x over previous
//
#include <hip/hip_runtime.h>
#include <cstdint>
#include <cmath>

// LSTM: B=64, T=2048, H=128, gates=4H=512. f32 throughout.
//
// Round 5 theory: R1-R4 all ~2ms because every variant broadcast-reads
// 256 KB/step/CU of h/weights through the LDS pipe (>=1000 cy/step at
// 256 B/clk) -- weight residency was never the binding constraint.
// Fix: h in registers, dot-product reduced cross-lane via DPP (VALU pipe).
//   lstm_rec_kernel: 64 blocks x 1024 threads = 128 groups of 8 lanes.
//   Group g owns hidden unit j=g (all 4 gate rows); lane l owns k-chunk
//   [16l,16l+16): 64 pinned weight floats + 16 h floats in regs.
//   Reduction: 3 DPP butterfly steps (xor1 quad_perm, xor2 quad_perm,
//   xor7 row_half_mirror). Gate math group-local (c in regs, replicated x8,
//   bitwise identical); transcendentals lane-split across the quad.
//   h redistribution: 1 float/group -> padded double-buffered h_lds,
//   ONE barrier/step, 64 B/thread chunk re-read (conflict-free).
// LDS traffic: 256 KB -> 64 KB/step/CU. New regime: VALU-issue-bound.

#define HID 128
#define G4  512
#define BB  64
#define TT  2048

#define PIN4(v) asm volatile("" : "+v"((v).x), "+v"((v).y), "+v"((v).z), "+v"((v).w))

template<int CTRL>
__device__ __forceinline__ float dpp_mov(float v) {
    return __int_as_float(__builtin_amdgcn_update_dpp(
        0, __float_as_int(v), CTRL, 0xF, 0xF, false));
}
// 8-lane sum: lanes 8a..8a+7 all end with the group total.
// xor1 = quad_perm(1,0,3,2)=0xB1, xor2 = quad_perm(2,3,0,1)=0x4E,
// xor7 = row_half_mirror=0x141 (cross-quad within the 8).
#define BF8(p) { p += dpp_mov<0xB1>(p); p += dpp_mov<0x4E>(p); p += dpp_mov<0x141>(p); }

// ---------------- input projection (unchanged structure; gate-interleaved dst)
#define DECL_W16(p) \
    float4 w0=(p)[0],  w1=(p)[1],  w2=(p)[2],  w3=(p)[3],  \
           w4=(p)[4],  w5=(p)[5],  w6=(p)[6],  w7=(p)[7],  \
           w8=(p)[8],  w9=(p)[9],  w10=(p)[10],w11=(p)[11],\
           w12=(p)[12],w13=(p)[13],w14=(p)[14],w15=(p)[15];
#define LOAD_W16(p) \
    w0=(p)[0];  w1=(p)[1];  w2=(p)[2];  w3=(p)[3];  \
    w4=(p)[4];  w5=(p)[5];  w6=(p)[6];  w7=(p)[7];  \
    w8=(p)[8];  w9=(p)[9];  w10=(p)[10];w11=(p)[11];\
    w12=(p)[12];w13=(p)[13];w14=(p)[14];w15=(p)[15];
#define PIN_W16 \
    PIN4(w0);  PIN4(w1);  PIN4(w2);  PIN4(w3);  PIN4(w4);  PIN4(w5);  \
    PIN4(w6);  PIN4(w7);  PIN4(w8);  PIN4(w9);  PIN4(w10); PIN4(w11); \
    PIN4(w12); PIN4(w13); PIN4(w14); PIN4(w15);
#define FMA4(i) { const float4 v = hp[i];                      \
    a0 = fmaf(w##i.x, v.x, a0); a1 = fmaf(w##i.y, v.y, a1);     \
    a2 = fmaf(w##i.z, v.z, a2); a3 = fmaf(w##i.w, v.w, a3); }
#define DOT64X \
    FMA4(0)  FMA4(1)  FMA4(2)  FMA4(3)  FMA4(4)  FMA4(5)  FMA4(6)  FMA4(7) \
    FMA4(8)  FMA4(9)  FMA4(10) FMA4(11) FMA4(12) FMA4(13) FMA4(14) FMA4(15)

__global__ __launch_bounds__(512)
__attribute__((amdgpu_waves_per_eu(4, 4)))
void xproj_kernel(const float* __restrict__ x, const float* __restrict__ W_ih,
                  const float* __restrict__ b_ih, const float* __restrict__ b_hh,
                  float* __restrict__ xg, int t0, int Tc) {
    __shared__ __align__(16) float xs[16 * HID];
    const int j    = threadIdx.x;                  // gate row 0..511
    const int row0 = blockIdx.x * 16;
    const int b    = row0 / Tc;
    const int tc0  = row0 % Tc;

    const float* xsrc = x + ((size_t)b * TT + (size_t)t0 + tc0) * HID;
    reinterpret_cast<float4*>(xs)[j] =
        reinterpret_cast<const float4*>(xsrc)[j];

    const float bias = b_ih[j] + b_hh[j];
    const float4* wr = reinterpret_cast<const float4*>(W_ih + (size_t)j * HID);
    DECL_W16(wr)
    PIN_W16
    __syncthreads();

    float acc[16];
    #pragma unroll
    for (int r = 0; r < 16; ++r) acc[r] = bias;
    #pragma unroll
    for (int r = 0; r < 16; ++r) {
        const float4* hp = reinterpret_cast<const float4*>(&xs[r * HID]);
        float a0 = 0.f, a1 = 0.f, a2 = 0.f, a3 = 0.f;
        DOT64X
        acc[r] += (a0 + a1) + (a2 + a3);
    }
    LOAD_W16(wr + 16)
    PIN_W16
    #pragma unroll
    for (int r = 0; r < 16; ++r) {
        const float4* hp = reinterpret_cast<const float4*>(&xs[r * HID]) + 16;
        float a0 = 0.f, a1 = 0.f, a2 = 0.f, a3 = 0.f;
        DOT64X
        acc[r] += (a0 + a1) + (a2 + a3);
    }

    // gate-interleaved layout: position = hid*4 + gate  (hid=j&127, gate=j>>7)
    float* dst = xg + ((size_t)b * Tc + tc0) * G4 + ((j & 127) << 2) + (j >> 7);
    #pragma unroll
    for (int r = 0; r < 16; ++r)
        dst[(size_t)r * G4] = acc[r];
}

// ---------------- recurrence
#define FMA_Q(P, A, B, C, D) \
  P = fmaf((A).x, hc0.x, P); P = fmaf((A).y, hc0.y, P); P = fmaf((A).z, hc0.z, P); P = fmaf((A).w, hc0.w, P); \
  P = fmaf((B).x, hc1.x, P); P = fmaf((B).y, hc1.y, P); P = fmaf((B).z, hc1.z, P); P = fmaf((B).w, hc1.w, P); \
  P = fmaf((C).x, hc2.x, P); P = fmaf((C).y, hc2.y, P); P = fmaf((C).z, hc2.z, P); P = fmaf((C).w, hc2.w, P); \
  P = fmaf((D).x, hc3.x, P); P = fmaf((D).y, hc3.y, P); P = fmaf((D).z, hc3.z, P); P = fmaf((D).w, hc3.w, P);

__global__ __launch_bounds__(1024)
__attribute__((amdgpu_waves_per_eu(4, 4)))
void lstm_rec_kernel(const float* __restrict__ xg, const float* __restrict__ h0,
                     const float* __restrict__ c0, const float* __restrict__ W_hh,
                     float* __restrict__ out, float* __restrict__ hstate,
                     float* __restrict__ cstate, int t0, int Tc) {
    // padded double buffer: value k lives at float offset 20*(k>>4)+(k&15)
    // -> chunk l base = 20l floats = 80l B: banks {0,20,8,28,16,4,24,12} distinct.
    __shared__ __align__(16) float h_lds[2][160];
    const int t = threadIdx.x;
    const int j = t >> 3;                          // hidden unit 0..127
    const int l = t & 7;                           // k-chunk
    const int b = blockIdx.x;

    // weights: rows q*128+j (q = gate i,f,g,o), cols [16l,16l+16)
    const float* wp = W_hh + (size_t)j * HID + 16 * l;
    const float4* W0 = reinterpret_cast<const float4*>(wp);
    const float4* W1 = reinterpret_cast<const float4*>(wp + 128 * HID);
    const float4* W2 = reinterpret_cast<const float4*>(wp + 256 * HID);
    const float4* W3 = reinterpret_cast<const float4*>(wp + 384 * HID);
    float4 w00=W0[0], w01=W0[1], w02=W0[2], w03=W0[3];
    float4 w10=W1[0], w11=W1[1], w12=W1[2], w13=W1[3];
    float4 w20=W2[0], w21=W2[1], w22=W2[2], w23=W2[3];
    float4 w30=W3[0], w31=W3[1], w32=W3[2], w33=W3[3];
    PIN4(w00); PIN4(w01); PIN4(w02); PIN4(w03);
    PIN4(w10); PIN4(w11); PIN4(w12); PIN4(w13);
    PIN4(w20); PIN4(w21); PIN4(w22); PIN4(w23);
    PIN4(w30); PIN4(w31); PIN4(w32); PIN4(w33);

    float c = (t0 == 0) ? c0[b * HID + j] : cstate[b * HID + j];  // same in group
    if (t < HID) {
        const int pi = 20 * (t >> 4) + (t & 15);
        h_lds[0][pi] = (t0 == 0) ? h0[b * HID + t] : hstate[b * HID + t];
    }
    __syncthreads();

    float4 hc0 = *reinterpret_cast<const float4*>(&h_lds[0][20 * l + 0]);
    float4 hc1 = *reinterpret_cast<const float4*>(&h_lds[0][20 * l + 4]);
    float4 hc2 = *reinterpret_cast<const float4*>(&h_lds[0][20 * l + 8]);
    float4 hc3 = *reinterpret_cast<const float4*>(&h_lds[0][20 * l + 12]);

    const float* xq   = xg  + (size_t)b * Tc * G4 + 4 * j;   // gate-interleaved
    float*       outb = out + ((size_t)b * TT + t0) * HID + j;
    float4 xn = *reinterpret_cast<const float4*>(xq);

    const int sel = t & 3;
    for (int tc = 0; tc < Tc; ++tc) {
        float4 xnn = xn;
        if (tc + 1 < Tc)                            // uniform branch
            xnn = *reinterpret_cast<const float4*>(xq + (size_t)(tc + 1) * G4);

        float p0 = 0.f, p1 = 0.f, p2 = 0.f, p3 = 0.f;
        FMA_Q(p0, w00, w01, w02, w03)
        FMA_Q(p1, w10, w11, w12, w13)
        FMA_Q(p2, w20, w21, w22, w23)
        FMA_Q(p3, w30, w31, w32, w33)
        BF8(p0) BF8(p1) BF8(p2) BF8(p3)             // all 8 lanes: full dots
        p0 += xn.x; p1 += xn.y; p2 += xn.z; p3 += xn.w;

        // lane-split transcendentals: lane sel owns gate sel's sigmoid.
        // gate 2 (g) uses tanh(x) = 2*sigmoid(2x)-1.
        const float xv = (sel == 0) ? p0 : (sel == 1) ? p1 : (sel == 2) ? p2 : p3;
        const float mm = (sel == 2) ? 2.f : 1.f;
        const float e  = __expf(-xv * mm);
        const float r  = 1.f / (1.f + e);           // sigmoid(mm*xv)
        const float vi = dpp_mov<0x00>(r);          // quad lane0 -> all
        const float vf = dpp_mov<0x55>(r);          // lane1
        const float vg = 2.f * dpp_mov<0xAA>(r) - 1.f;  // lane2, tanh fix
        const float vo = dpp_mov<0xFF>(r);          // lane3
        c = fmaf(vf, c, vi * vg);
        const float e2 = __expf(-2.f * c);
        const float th = 2.f / (1.f + e2) - 1.f;    // tanh(c)
        const float h  = vo * th;

        const int nb = (tc + 1) & 1;
        if (l == 0) {
            h_lds[nb][20 * (j >> 4) + (j & 15)] = h;
            outb[(size_t)tc * HID] = h;             // 8 consecutive floats/wave
        }
        __syncthreads();                            // ONE barrier per step
        hc0 = *reinterpret_cast<const float4*>(&h_lds[nb][20 * l + 0]);
        hc1 = *reinterpret_cast<const float4*>(&h_lds[nb][20 * l + 4]);
        hc2 = *reinterpret_cast<const float4*>(&h_lds[nb][20 * l + 8]);
        hc3 = *reinterpret_cast<const float4*>(&h_lds[nb][20 * l + 12]);
        xn = xnn;
    }
    if (l == 0) cstate[b * HID + j] = c;
    if (t < HID) {
        const int pi = 20 * (t >> 4) + (t & 15);
        hstate[b * HID + t] = h_lds[Tc & 1][pi];
    }
}

extern "C" void kernel_launch(void* const* d_in, const int* in_sizes, int n_in,
                              void* d_out, int out_size, void* d_ws, size_t ws_size,
                              hipStream_t stream) {
    const float* x    = (const float*)d_in[0];
    const float* h0   = (const float*)d_in[1];
    const float* c0   = (const float*)d_in[2];
    const float* W_ih = (const float*)d_in[3];
    const float* W_hh = (const float*)d_in[4];
    const float* b_ih = (const float*)d_in[5];
    const float* b_hh = (const float*)d_in[6];
    float* out = (float*)d_out;

    char*  ws     = (char*)d_ws;
    float* hstate = (float*)ws;                    // 32 KB
    float* cstate = (float*)(ws + 32768);          // 32 KB
    float* xg     = (float*)(ws + 65536);

    const size_t per_t = (size_t)BB * G4 * sizeof(float);   // 128 KB per timestep
    size_t avail = ws_size > 65536 ? ws_size - 65536 : 0;
    long long tc_ll = (long long)(avail / per_t);
    int Tc = tc_ll > TT ? TT : (int)tc_ll;
    Tc = (Tc / 64) * 64;
    if (Tc < 64) Tc = 64;

    for (int t0 = 0; t0 < TT; t0 += Tc) {
        const int Tcur = (TT - t0 < Tc) ? (TT - t0) : Tc;
        xproj_kernel<<<dim3(4 * Tcur), dim3(512), 0, stream>>>(x, W_ih, b_ih, b_hh,
                                                               xg, t0, Tcur);
        lstm_rec_kernel<<<dim3(BB), dim3(1024), 0, stream>>>(xg, h0, c0, W_hh, out,
                                                             hstate, cstate, t0, Tcur);
    }
}